// Round 2
// baseline (329.914 us; speedup 1.0000x reference)
//
#include <hip/hip_runtime.h>
#include <math.h>

// GEBLNet, weight-stationary design.
// Block = 320 threads (5 waves), processes PPB points sequentially.
// Thread roles (loop-invariant, hoisted):
//   layer2 B-phase: t<300 owns (uu=t/25, vv=t%25); w2 row lives in 50 VGPRs.
//   layer1 B-phase: t<156 owns (u1=t/13, v1=t%13); w1 row lives in 26 VGPRs.
// Per point: B[u][v][:] accumulated in registers from wave-uniform (broadcast)
// LDS reads of Wext; layer1 stores full 3x3 partial (needed to build Wext2);
// layer2 only needs the trace -> 9-cmac diagonal + 2-float Td write.
// Head output for point pi-1 is computed in phase A of iteration pi (overlaps
// the next point's Wext1 build).

#define THRESH 0.001f
#define PPB 8

__global__ __launch_bounds__(320) void geblnet_kernel(
    const float* __restrict__ x,      // (8192, 10, 3, 3, 2)
    const float* __restrict__ w1,     // (12,13,13,2)
    const float* __restrict__ w2,     // (12,25,25,2)
    const float* __restrict__ dw,     // (24,)
    const float* __restrict__ db,     // (1,)
    float* __restrict__ out)          // (8192,)
{
    const int t = threadIdx.x;

    __shared__ float We[25][18];      // current layer's extended channels
    __shared__ float Pm[12][13][18];  // layer1 partials (full matrices)
    __shared__ float Hs[12][18];      // layer1 H
    __shared__ float Td[300][2];      // per-(u,v) trace contributions
    __shared__ float g_s[12], tra_s[12], trr_s[12], tri_s[12];

    // loop-invariant roles
    const int uu = t / 25, vv = t % 25;   // layer2 pair (t<300)
    const int u1 = t / 13, v1 = t % 13;   // layer1 pair (t<156)
    const int ru = t / 18, rq = t % 18;   // reduce role (t<216)
    const int wv = t / 9,  wik = t % 9;   // Wext-build role
    const int wi = wik / 3, wj = wik % 3;

    // weight preload (stays in VGPRs for the whole kernel)
    float c1r[13], c1i[13];
    if (t < 156) {
        const float* wp = w1 + t * 26;
        #pragma unroll
        for (int w = 0; w < 13; ++w) { c1r[w] = wp[2*w]; c1i[w] = wp[2*w+1]; }
    }
    float c2r[25], c2i[25];
    if (t < 300) {
        const float* wp = w2 + t * 50;
        #pragma unroll
        for (int w = 0; w < 25; ++w) { c2r[w] = wp[2*w]; c2i[w] = wp[2*w+1]; }
    }

    const long base_p = (long)blockIdx.x * PPB;

    for (int pi = 0; pi <= PPB; ++pi) {
        // ---- phase A: build Wext1(point pi) + head output for point pi-1
        if (pi < PPB && t < 117) {
            const float* xp = x + (base_p + pi) * 180;
            float re, im;
            if (wv < 6)       { const float* s = xp + (4 + wv) * 18 + wik * 2;          re = s[0]; im =  s[1]; }
            else if (wv < 12) { const float* s = xp + (wv - 2) * 18 + (wj * 3 + wi) * 2; re = s[0]; im = -s[1]; }
            else              { re = (wi == wj) ? 1.f : 0.f; im = 0.f; }
            We[wv][2*wik] = re; We[wv][2*wik+1] = im;
        }
        if (pi > 0 && t == 316) {
            float m = 0.f;
            #pragma unroll
            for (int u = 0; u < 12; ++u) m += tra_s[u];
            float inv = 1.f / fmaxf(m * (1.f / 12.f), THRESH);
            float acc = db[0];
            #pragma unroll
            for (int u = 0; u < 12; ++u) {
                float sc = g_s[u] * inv * (1.f / 3.f);
                acc += sc * trr_s[u] * dw[2*u] + sc * tri_s[u] * dw[2*u+1];
            }
            out[base_p + pi - 1] = acc;
        }
        if (pi == PPB) break;
        __syncthreads();

        // ---- B1 + full partial1 (t<156): pure-FMA stream, We reads broadcast
        if (t < 156) {
            float br[9], bi[9];
            #pragma unroll
            for (int q = 0; q < 9; ++q) { br[q] = 0.f; bi[q] = 0.f; }
            #pragma unroll
            for (int w = 0; w < 13; ++w) {
                float wr = c1r[w], wim = c1i[w];
                #pragma unroll
                for (int q = 0; q < 9; ++q) {
                    float er = We[w][2*q], ei = We[w][2*q+1];
                    br[q] += wr * er - wim * ei;
                    bi[q] += wr * ei + wim * er;
                }
            }
            float pr[9], pm[9];
            #pragma unroll
            for (int q = 0; q < 9; ++q) { pr[q] = 0.f; pm[q] = 0.f; }
            #pragma unroll
            for (int i = 0; i < 3; ++i) {
                #pragma unroll
                for (int j = 0; j < 3; ++j) {
                    float er = We[v1][2*(i*3+j)], ei = We[v1][2*(i*3+j)+1];
                    #pragma unroll
                    for (int k = 0; k < 3; ++k) {
                        pr[i*3+k] += er * br[j*3+k] - ei * bi[j*3+k];
                        pm[i*3+k] += er * bi[j*3+k] + ei * br[j*3+k];
                    }
                }
            }
            #pragma unroll
            for (int q = 0; q < 9; ++q) { Pm[u1][v1][2*q] = pr[q]; Pm[u1][v1][2*q+1] = pm[q]; }
            Td[t][0] = pr[0] + pr[4] + pr[8];
            Td[t][1] = pm[0] + pm[4] + pm[8];
        }
        __syncthreads();

        // ---- reduce1 -> Hs, + trace1 (separate wave)
        if (t < 216) {
            float s = 0.f;
            #pragma unroll
            for (int v = 0; v < 13; ++v) s += Pm[ru][v][rq];
            Hs[ru][rq] = s;
        } else if (t >= 256 && t < 268) {
            int u = t - 256;
            float rr = 0.f, ri = 0.f;
            #pragma unroll
            for (int v = 0; v < 13; ++v) { rr += Td[u*13+v][0]; ri += Td[u*13+v][1]; }
            float s = rr > 0.f ? rr : 0.f;
            g_s[u] = s;
            tra_s[u] = s * sqrtf(rr * rr + ri * ri);
        }
        __syncthreads();

        // ---- build Wext2 (norm recomputed per-thread: saves a barrier)
        if (t < 225) {
            float m = 0.f;
            #pragma unroll
            for (int u = 0; u < 12; ++u) m += tra_s[u];
            float inv = 1.f / fmaxf(m * (1.f / 12.f), THRESH);
            float re, im;
            if (wv < 12) {
                float sc = g_s[wv] * inv;
                re = sc * Hs[wv][2*wik]; im = sc * Hs[wv][2*wik+1];
            } else if (wv < 24) {
                int sv = wv - 12;
                float sc = g_s[sv] * inv;
                re = sc * Hs[sv][2*(wj*3+wi)]; im = -sc * Hs[sv][2*(wj*3+wi)+1];
            } else { re = (wi == wj) ? 1.f : 0.f; im = 0.f; }
            We[wv][2*wik] = re; We[wv][2*wik+1] = im;
        }
        __syncthreads();

        // ---- B2 + diagonal-only trace (t<300): 900+36 FMA per thread
        if (t < 300) {
            float br[9], bi[9];
            #pragma unroll
            for (int q = 0; q < 9; ++q) { br[q] = 0.f; bi[q] = 0.f; }
            #pragma unroll
            for (int w = 0; w < 25; ++w) {
                float wr = c2r[w], wim = c2i[w];
                #pragma unroll
                for (int q = 0; q < 9; ++q) {
                    float er = We[w][2*q], ei = We[w][2*q+1];
                    br[q] += wr * er - wim * ei;
                    bi[q] += wr * ei + wim * er;
                }
            }
            float dr = 0.f, di = 0.f;   // tr(We[vv] @ B)
            #pragma unroll
            for (int i = 0; i < 3; ++i) {
                #pragma unroll
                for (int j = 0; j < 3; ++j) {
                    float er = We[vv][2*(i*3+j)], ei = We[vv][2*(i*3+j)+1];
                    dr += er * br[j*3+i] - ei * bi[j*3+i];
                    di += er * bi[j*3+i] + ei * br[j*3+i];
                }
            }
            Td[t][0] = dr; Td[t][1] = di;
        }
        __syncthreads();

        // ---- trace2 (t<12), feeds the head in next iteration's phase A
        if (t < 12) {
            float rr = 0.f, ri = 0.f;
            #pragma unroll
            for (int v = 0; v < 25; ++v) { rr += Td[t*25+v][0]; ri += Td[t*25+v][1]; }
            float s = rr > 0.f ? rr : 0.f;
            g_s[t] = s;
            tra_s[t] = s * sqrtf(rr * rr + ri * ri);
            trr_s[t] = rr; tri_s[t] = ri;
        }
        __syncthreads();
    }
}

extern "C" void kernel_launch(void* const* d_in, const int* in_sizes, int n_in,
                              void* d_out, int out_size, void* d_ws, size_t ws_size,
                              hipStream_t stream) {
    const float* x  = (const float*)d_in[0];
    const float* w1 = (const float*)d_in[1];
    const float* w2 = (const float*)d_in[2];
    const float* dw = (const float*)d_in[3];
    const float* db = (const float*)d_in[4];
    float* outp = (float*)d_out;
    const int npts = out_size;            // 8192
    const int nblocks = npts / PPB;       // 1024
    geblnet_kernel<<<nblocks, 320, 0, stream>>>(x, w1, w2, dw, db, outp);
}

// Round 3
// 197.150 us; speedup vs baseline: 1.6734x; 1.6734x over previous
//
#include <hip/hip_runtime.h>
#include <math.h>

// GEBLNet via Gram-matrix reduction.
// Layer 2 output is only consumed through its trace:
//   T[u] = sum_{v,w} w2[u,v,w] * tr(We2[v] @ We2[w]) = sum_{v,w} w2[u,v,w]*G[v,w]
// With We2 = [A_0..A_11, A_0^H..A_11^H, I] (A = scaled layer-1 outputs):
//   G[a,b]         = S[a,b]  = tr(A_a A_b)        (symmetric)
//   G[a,12+b]      = Hm[a,b] = tr(A_a A_b^H);  G[12+b,a] = Hm[a,b]
//   G[b,12+a]      = conj(Hm[a,b]);            G[12+a,b] = conj(Hm[a,b])
//   G[12+a,12+b]   = conj(S[a,b]);  G[a,24]=tr(A_a); G[24,24]=3
// All w2 coefficients fold (per launch) into CT[u][169] float4 acting on the
// 169 unique values [78 S | 78 Hm | 12 tr | 1 const]:
//   TRe += c0*vr + c1*vi ; TIm += c2*vr + c3*vi
// Layer 1 computed exactly (full H needed): thread=(p,u,k) owns column k of
// H[u], We1 k-column preloaded to 39 regs -> B-inner-loop is LDS-free.

#define NPTS 8192
#define NP 7
#define THRESH 0.001f

__global__ void geblnet_setup(const float* __restrict__ w2,
                              float4* __restrict__ CT) {
    int j = blockIdx.x * blockDim.x + threadIdx.x;
    if (j >= 12 * 169) return;
    int u = j / 169, it = j % 169;
    const float* W = w2 + u * 25 * 25 * 2;
#define WR(v, w) W[((v) * 25 + (w)) * 2]
#define WI(v, w) W[((v) * 25 + (w)) * 2 + 1]
    float c0, c1, c2, c3;
    if (it < 78) {                       // S pairs, a<=b
        int q = it, a = 0;
        while (q >= 12 - a) { q -= 12 - a; ++a; }
        int b = a + q;
        float ar = WR(a, b) + (a != b ? WR(b, a) : 0.f);
        float ai = WI(a, b) + (a != b ? WI(b, a) : 0.f);
        float br = WR(12 + a, 12 + b) + (a != b ? WR(12 + b, 12 + a) : 0.f);
        float bi = WI(12 + a, 12 + b) + (a != b ? WI(12 + b, 12 + a) : 0.f);
        c0 = ar + br; c1 = bi - ai; c2 = ai + bi; c3 = ar - br;
    } else if (it < 156) {               // Hm pairs, a<=b
        int q = it - 78, a = 0;
        while (q >= 12 - a) { q -= 12 - a; ++a; }
        int b = a + q;
        if (a != b) {
            float gr = WR(a, 12 + b) + WR(12 + b, a);
            float gi = WI(a, 12 + b) + WI(12 + b, a);
            float dr = WR(b, 12 + a) + WR(12 + a, b);
            float di = WI(b, 12 + a) + WI(12 + a, b);
            c0 = gr + dr; c1 = di - gi; c2 = gi + di; c3 = gr - dr;
        } else {                          // Hm[a,a] is exactly real
            float er = WR(a, 12 + a) + WR(12 + a, a);
            float ei = WI(a, 12 + a) + WI(12 + a, a);
            c0 = er; c1 = 0.f; c2 = ei; c3 = 0.f;
        }
    } else if (it < 168) {               // trace terms
        int a = it - 156;
        float fr = WR(a, 24) + WR(24, a), fi = WI(a, 24) + WI(24, a);
        float pr = WR(12 + a, 24) + WR(24, 12 + a);
        float pi = WI(12 + a, 24) + WI(24, 12 + a);
        c0 = fr + pr; c1 = pi - fi; c2 = fi + pi; c3 = fr - pr;
    } else {                             // unit-unit
        c0 = 3.f * WR(24, 24); c1 = 0.f; c2 = 3.f * WI(24, 24); c3 = 0.f;
    }
    CT[j] = make_float4(c0, c1, c2, c3);
#undef WR
#undef WI
}

__global__ __launch_bounds__(256) void geblnet_main(
    const float2* __restrict__ x2,      // (8192, 10, 9) complex
    const float2* __restrict__ w1_2,    // (12,13,13) complex
    const float* __restrict__ dw,       // (24,)
    const float* __restrict__ db,       // (1,)
    const float4* __restrict__ CT,      // (12,169)
    float* __restrict__ out)            // (8192,)
{
    __shared__ float2 We1[NP][117];     // layer-1 extended channels
    __shared__ float2 Hs[NP][108];      // layer-1 outputs H[u] (12 x 3x3)
    __shared__ float2 GV[NP][169];      // Gram values [S|Hm|t|1]
    __shared__ float2 Tpar[NP][36];     // contraction partials [u][q]
    __shared__ float2 tr1[NP][12];
    __shared__ float  sc1[NP][12];

    const int t = threadIdx.x;
    const int pbase = blockIdx.x * NP;

    // ---- phase 1: build We1 (NP*117 jobs)
    for (int j = t; j < NP * 117; j += 256) {
        int p = j / 117, rr = j % 117;
        if (pbase + p >= NPTS) continue;
        int v = rr / 9, ik = rr % 9;
        float2 val;
        if (v < 6) {
            val = x2[(size_t)(pbase + p) * 90 + (4 + v) * 9 + ik];
        } else if (v < 12) {
            int i = ik / 3, jj = ik % 3;
            float2 s = x2[(size_t)(pbase + p) * 90 + (v - 2) * 9 + jj * 3 + i];
            val = make_float2(s.x, -s.y);
        } else {
            int i = ik / 3, jj = ik % 3;
            val = make_float2((i == jj) ? 1.f : 0.f, 0.f);
        }
        We1[p][rr] = val;
    }
    __syncthreads();

    // ---- phase 2: layer 1, thread=(p,u,k), 252 active
    if (t < NP * 36) {
        int p = t / 36, r = t % 36, u = r / 3, k = r % 3;
        if (pbase + p < NPTS) {
            // preload k-column of every We1 channel (39 complex -> regs)
            float2 wc[13][3];
            #pragma unroll
            for (int w = 0; w < 13; ++w)
                #pragma unroll
                for (int jj = 0; jj < 3; ++jj)
                    wc[w][jj] = We1[p][w * 9 + jj * 3 + k];
            float2 h0 = make_float2(0.f, 0.f), h1 = h0, h2 = h0;
            for (int v = 0; v < 13; ++v) {
                const float2* wr = w1_2 + (u * 13 + v) * 13;
                float2 b0 = make_float2(0.f, 0.f), b1 = b0, b2 = b0;
                #pragma unroll
                for (int w = 0; w < 13; ++w) {
                    float2 c = wr[w];
                    b0.x += c.x * wc[w][0].x - c.y * wc[w][0].y;
                    b0.y += c.x * wc[w][0].y + c.y * wc[w][0].x;
                    b1.x += c.x * wc[w][1].x - c.y * wc[w][1].y;
                    b1.y += c.x * wc[w][1].y + c.y * wc[w][1].x;
                    b2.x += c.x * wc[w][2].x - c.y * wc[w][2].y;
                    b2.y += c.x * wc[w][2].y + c.y * wc[w][2].x;
                }
                // H[u][i,k] += sum_j We1[v][i,j] * b_j
                #pragma unroll
                for (int i = 0; i < 3; ++i) {
                    float2 a0 = We1[p][v * 9 + i * 3 + 0];
                    float2 a1 = We1[p][v * 9 + i * 3 + 1];
                    float2 a2 = We1[p][v * 9 + i * 3 + 2];
                    float hr = a0.x * b0.x - a0.y * b0.y
                             + a1.x * b1.x - a1.y * b1.y
                             + a2.x * b2.x - a2.y * b2.y;
                    float hi = a0.x * b0.y + a0.y * b0.x
                             + a1.x * b1.y + a1.y * b1.x
                             + a2.x * b2.y + a2.y * b2.x;
                    if (i == 0) { h0.x += hr; h0.y += hi; }
                    else if (i == 1) { h1.x += hr; h1.y += hi; }
                    else { h2.x += hr; h2.y += hi; }
                }
            }
            Hs[p][u * 9 + 0 + k] = h0;
            Hs[p][u * 9 + 3 + k] = h1;
            Hs[p][u * 9 + 6 + k] = h2;
        }
    }
    __syncthreads();

    // ---- phase 3: traces + gerelu + trnorm scales (NP threads)
    if (t < NP && pbase + t < NPTS) {
        int p = t;
        float m = 0.f; float g[12]; float2 tl[12];
        #pragma unroll
        for (int u = 0; u < 12; ++u) {
            float2 a = Hs[p][u * 9 + 0], b = Hs[p][u * 9 + 4], c = Hs[p][u * 9 + 8];
            float2 tt = make_float2(a.x + b.x + c.x, a.y + b.y + c.y);
            tl[u] = tt;
            float gg = tt.x > 0.f ? tt.x : 0.f;
            g[u] = gg;
            m += gg * sqrtf(tt.x * tt.x + tt.y * tt.y);
        }
        float inv = 1.f / fmaxf(m * (1.f / 12.f), THRESH);
        #pragma unroll
        for (int u = 0; u < 12; ++u) { sc1[p][u] = g[u] * inv; tr1[p][u] = tl[u]; }
    }
    __syncthreads();

    // ---- phase 4: Gram values (NP*169 jobs)
    for (int j = t; j < NP * 169; j += 256) {
        int p = j / 169, it = j % 169;
        if (pbase + p >= NPTS) continue;
        float2 val;
        if (it < 156) {
            int q = it < 78 ? it : it - 78;
            int a = 0;
            while (q >= 12 - a) { q -= 12 - a; ++a; }
            int b = a + q;
            const float2* Ha = &Hs[p][a * 9];
            const float2* Hb = &Hs[p][b * 9];
            float s = sc1[p][a] * sc1[p][b];
            float vr = 0.f, vi = 0.f;
            if (it < 78) {                    // S = tr(Aa Ab)
                #pragma unroll
                for (int i = 0; i < 3; ++i)
                    #pragma unroll
                    for (int jj = 0; jj < 3; ++jj) {
                        float2 A = Ha[i * 3 + jj], B = Hb[jj * 3 + i];
                        vr += A.x * B.x - A.y * B.y;
                        vi += A.x * B.y + A.y * B.x;
                    }
            } else {                          // Hm = tr(Aa Ab^H)
                #pragma unroll
                for (int e = 0; e < 9; ++e) {
                    float2 A = Ha[e], B = Hb[e];
                    vr += A.x * B.x + A.y * B.y;
                    vi += A.y * B.x - A.x * B.y;
                }
            }
            val = make_float2(s * vr, s * vi);
        } else if (it < 168) {
            int a = it - 156;
            float s = sc1[p][a]; float2 tt = tr1[p][a];
            val = make_float2(s * tt.x, s * tt.y);
        } else {
            val = make_float2(1.f, 0.f);
        }
        GV[p][it] = val;
    }
    __syncthreads();

    // ---- phase 5: coefficient contraction, thread=(q,p,u), q-major
    if (t < 252) {
        int q = t / 84, r = t % 84, p = r / 12, u = r % 12;
        if (pbase + p < NPTS) {
            int i0 = q * 57, i1 = (q == 2) ? 169 : i0 + 57;
            const float4* Cu = CT + u * 169;
            float tre = 0.f, tim = 0.f;
            for (int it = i0; it < i1; ++it) {
                float4 c = Cu[it];
                float2 gv = GV[p][it];
                tre += c.x * gv.x + c.y * gv.y;
                tim += c.z * gv.x + c.w * gv.y;
            }
            Tpar[p][u * 3 + q] = make_float2(tre, tim);
        }
    }
    __syncthreads();

    // ---- phase 6: layer-2 gerelu + trnorm + dense head (NP threads)
    if (t < NP && pbase + t < NPTS) {
        int p = t;
        float m = 0.f; float2 T[12]; float gg[12];
        #pragma unroll
        for (int u = 0; u < 12; ++u) {
            float2 A = Tpar[p][u * 3], B = Tpar[p][u * 3 + 1], C = Tpar[p][u * 3 + 2];
            float2 tt = make_float2(A.x + B.x + C.x, A.y + B.y + C.y);
            T[u] = tt;
            float g = tt.x > 0.f ? tt.x : 0.f;
            gg[u] = g;
            m += g * sqrtf(tt.x * tt.x + tt.y * tt.y);
        }
        float inv = 1.f / fmaxf(m * (1.f / 12.f), THRESH);
        float acc = db[0];
        #pragma unroll
        for (int u = 0; u < 12; ++u) {
            float s = gg[u] * inv * (1.f / 3.f);
            acc += s * (T[u].x * dw[2 * u] + T[u].y * dw[2 * u + 1]);
        }
        out[pbase + p] = acc;
    }
}

extern "C" void kernel_launch(void* const* d_in, const int* in_sizes, int n_in,
                              void* d_out, int out_size, void* d_ws, size_t ws_size,
                              hipStream_t stream) {
    const float* x  = (const float*)d_in[0];
    const float* w1 = (const float*)d_in[1];
    const float* w2 = (const float*)d_in[2];
    const float* dw = (const float*)d_in[3];
    const float* db = (const float*)d_in[4];
    float* outp = (float*)d_out;
    float4* CT = (float4*)d_ws;          // 12*169*16 B = 32448 B

    geblnet_setup<<<(12 * 169 + 255) / 256, 256, 0, stream>>>(w2, CT);

    const int nblocks = (NPTS + NP - 1) / NP;   // 1171
    geblnet_main<<<nblocks, 256, 0, stream>>>(
        (const float2*)x, (const float2*)w1, dw, db, CT, outp);
}